// Round 18
// baseline (579.919 us; speedup 1.0000x reference)
//
#include <hip/hip_runtime.h>
#include <stdint.h>

#define NPTS 2048
#define BATCH 4
#define KNN 20
#define EPSV 1e-5f

typedef short bf16x8 __attribute__((ext_vector_type(8)));
typedef float f32x4 __attribute__((ext_vector_type(4)));

__device__ __forceinline__ unsigned short f2bf(float f){
  union { float f; uint32_t u; } x; x.f = f;
  uint32_t u = x.u;
  uint32_t r = (u + 0x7fffu + ((u >> 16) & 1u)) >> 16;
  return (unsigned short)r;
}
__device__ __forceinline__ float bf2f(unsigned short h){
  union { uint32_t u; float f; } x; x.u = ((uint32_t)h) << 16;
  return x.f;
}

// ---------------- weight folding: bn-fold -> bf16 [t][oc(128)][ic(128)] ----------------
__global__ __launch_bounds__(256) void fold_wpk(const float* __restrict__ W, const float* __restrict__ g,
    const float* __restrict__ bb, const float* __restrict__ m, const float* __restrict__ vv,
    unsigned short* __restrict__ w, float* __restrict__ bias){
  int e = blockIdx.x*256 + threadIdx.x;
  if (e < 128){
    float s = g[e] / sqrtf(vv[e] + EPSV);
    bias[e] = bb[e] - m[e]*s;
  }
  if (e < 9*128*128){
    int t = e >> 14;
    int o = (e >> 7) & 127;
    int i = e & 127;
    int kh = t/3, kw = t - 3*kh;
    float s = g[o] / sqrtf(vv[o] + EPSV);
    float wv = W[((o*128 + i)*3 + kh)*3 + kw] * s;
    w[(t*128 + o)*128 + i] = f2bf(wv);
  }
}

__global__ __launch_bounds__(256) void fold_img(const float* __restrict__ Wimgc, const float* __restrict__ bimgc,
    const float* __restrict__ Wimg, const float* __restrict__ bimg,
    float* __restrict__ Wf, float* __restrict__ bf){
  int e = blockIdx.x*256 + threadIdx.x;
  if (e < 384){
    int j = e >> 7, c = e & 127;
    float s = 0.f;
    for (int o = 0; o < 128; ++o) s += Wimg[j*128+o] * Wimgc[o*128+c];
    Wf[e] = s;
  }
  if (e < 3){
    float s = bimg[e];
    for (int o = 0; o < 128; ++o) s += Wimg[e*128+o] * bimgc[o];
    bf[e] = s;
  }
}

// ---------------- point features (sq in fp64 to match numpy ref) ----------------
__global__ __launch_bounds__(256) void prep_x(const float* __restrict__ opc, const float* __restrict__ Win,
    const float* __restrict__ bin, float* __restrict__ x, double* __restrict__ sq){
  int p = blockIdx.x*256 + threadIdx.x;
  if (p >= BATCH*NPTS) return;
  float a = opc[p*3], b = opc[p*3+1], c = opc[p*3+2];
  double ad = a, bd = b, cd = c;
  sq[p] = (ad*ad + bd*bd) + cd*cd;
  for (int o = 0; o < 64; ++o)
    x[p*64+o] = a*Win[o*3] + b*Win[o*3+1] + c*Win[o*3+2] + bin[o];
}

__global__ __launch_bounds__(256) void prep_uv(const float* __restrict__ x, const float* __restrict__ Wg,
    float* __restrict__ u, float* __restrict__ v){
  int e = blockIdx.x*256 + threadIdx.x;
  if (e >= BATCH*NPTS*128) return;
  int p = e >> 7, o = e & 127;
  const float* xr = x + p*64;
  const float* w = Wg + o*128;
  float su = 0.f, sv = 0.f;
  for (int c = 0; c < 64; ++c){
    float xv = xr[c];
    sv += w[c]*xv;
    su += (w[64+c] - w[c])*xv;
  }
  u[e] = su; v[e] = sv;
}

// ---------------- exact top-K (smallest d2), fp64, quarter-cached minima ----------------
__device__ __forceinline__ void knn_merge(double va, int ia, double vb, int ib,
                                          double& vo, int& io){
  if (vb < va || (vb == va && ib < ia)){ vo = vb; io = ib; }
  else { vo = va; io = ia; }
}

__device__ __forceinline__ void knn_scan_q(const double* __restrict__ d, int lane, int qt,
                                           double& vq, int& iq){
  double v0 = 1.0e300, v1 = 1.0e300;
  int i0 = -1, i1 = -1;
  int kb = qt*8;
  #pragma unroll
  for (int k2 = 0; k2 < 8; k2 += 2){
    int m0 = lane + (kb + k2)*64;
    int m1 = lane + (kb + k2 + 1)*64;
    double a0 = d[m0];
    double a1 = d[m1];
    if (a0 < v0){ v0 = a0; i0 = m0; }
    if (a1 < v1){ v1 = a1; i1 = m1; }
  }
  knn_merge(v0, i0, v1, i1, vq, iq);
}

__global__ __launch_bounds__(128) void knn_k(const float* __restrict__ pc, const double* __restrict__ sq,
    int* __restrict__ idx){
  __shared__ double dd[2][NPTS];
  int wave = threadIdx.x >> 6, lane = threadIdx.x & 63;
  int q = blockIdx.x*2 + wave;
  int b = q >> 11, n = q & 2047;
  const float* pb = pc + (size_t)b*NPTS*3;
  const double* sqb = sq + b*NPTS;
  double qx = pb[n*3], qy = pb[n*3+1], qz = pb[n*3+2];
  double sn = sqb[n];
  double* d = dd[wave];
  double vq[4]; int iq[4];
  #pragma unroll
  for (int t = 0; t < 4; ++t){ vq[t] = 1.0e300; iq[t] = -1; }
  #pragma unroll
  for (int k = 0; k < 32; ++k){
    int m = lane + k*64;
    double px = pb[m*3], py = pb[m*3+1], pz = pb[m*3+2];
    double dot = (qx*px + qy*py) + qz*pz;
    double val = (sn + sqb[m]) - 2.0*dot;
    d[m] = val;
    const int qt = k >> 3;
    if (val < vq[qt]){ vq[qt] = val; iq[qt] = m; }
  }
  double bv; int bi;
  {
    double m0, m1; int j0, j1;
    knn_merge(vq[0], iq[0], vq[1], iq[1], m0, j0);
    knn_merge(vq[2], iq[2], vq[3], iq[3], m1, j1);
    knn_merge(m0, j0, m1, j1, bv, bi);
  }
  for (int it = 0; it < KNN; ++it){
    double v = bv; int i = bi;
    #pragma unroll
    for (int s = 32; s; s >>= 1){
      double ov = __shfl_xor(v, s);
      int oi = __shfl_xor(i, s);
      if (ov < v || (ov == v && oi < i)){ v = ov; i = oi; }
    }
    if (lane == 0) idx[q*KNN + it] = i;
    if ((i & 63) == lane){
      d[i] = 1.0e300;
      int qt = i >> 9;
      knn_scan_q(d, lane, qt, vq[qt], iq[qt]);
      double m0, m1; int j0, j1;
      knn_merge(vq[0], iq[0], vq[1], iq[1], m0, j0);
      knn_merge(vq[2], iq[2], vq[3], iq[3], m1, j1);
      knn_merge(m0, j0, m1, j1, bv, bi);
    }
  }
}

// ---------------- groupnorm statistics ----------------
__global__ __launch_bounds__(256) void stats_k(const float* __restrict__ u, const float* __restrict__ v,
    const int* __restrict__ idx, float* __restrict__ sums){
  int blk = blockIdx.x;
  int b = blk >> 7;
  int n0 = (blk & 127) * 16;
  int tid = threadIdx.x;
  __shared__ int sidx[16*KNN];
  for (int i = tid; i < 16*KNN; i += 256)
    sidx[i] = idx[(b*NPTS + n0 + i/KNN)*KNN + (i % KNN)];
  __syncthreads();
  int c = tid & 127;
  int h = tid >> 7;
  float s = 0.f, ss = 0.f;
  for (int nl = 0; nl < 16; ++nl){
    float uv = u[((b*NPTS + n0 + nl) << 7) + c];
    for (int k = h; k < KNN; k += 2){
      int m = sidx[nl*KNN + k];
      float y = v[((b*NPTS + m) << 7) + c] + uv;
      s += y; ss += y*y;
    }
  }
  for (int msk = 1; msk < 32; msk <<= 1){
    s += __shfl_xor(s, msk);
    ss += __shfl_xor(ss, msk);
  }
  if ((tid & 31) == 0){
    int g = c >> 5;
    atomicAdd(&sums[(b*4 + g)*2 + 0], s);
    atomicAdd(&sums[(b*4 + g)*2 + 1], ss);
  }
}

// ---------------- normalize + lrelu + max_k + proj ----------------
__global__ __launch_bounds__(256) void fcomp_k(const float* __restrict__ u, const float* __restrict__ v,
    const int* __restrict__ idx, const float* __restrict__ sums,
    const float* __restrict__ gng, const float* __restrict__ gnb,
    const float* __restrict__ Wp, const float* __restrict__ bp, float* __restrict__ f){
  int blk = blockIdx.x;
  int b = blk >> 7;
  int n0 = (blk & 127) * 16;
  int tid = threadIdx.x;
  __shared__ int sidx[16*KNN];
  __shared__ float fpre[16*128];
  __shared__ float smu[4], sinv[4];
  if (tid < 4){
    const float cnt = 2048.0f*20.0f*32.0f;
    float sm = sums[(b*4 + tid)*2 + 0];
    float s2 = sums[(b*4 + tid)*2 + 1];
    float mu = sm/cnt;
    float var = s2/cnt - mu*mu;
    smu[tid] = mu;
    sinv[tid] = 1.0f / sqrtf(var + EPSV);
  }
  for (int i = tid; i < 16*KNN; i += 256)
    sidx[i] = idx[(b*NPTS + n0 + i/KNN)*KNN + (i % KNN)];
  __syncthreads();
  for (int e = tid; e < 2048; e += 256){
    int nl = e >> 7, c = e & 127;
    int g = c >> 5;
    float uv = u[((b*NPTS + n0 + nl) << 7) + c];
    float mu = smu[g], inv = sinv[g], gg = gng[c], gb = gnb[c];
    float best = -3.0e38f;
    for (int k = 0; k < KNN; ++k){
      int m = sidx[nl*KNN + k];
      float y = v[((b*NPTS + m) << 7) + c] + uv;
      float z = (y - mu)*inv*gg + gb;
      z = z >= 0.f ? z : 0.2f*z;
      best = fmaxf(best, z);
    }
    fpre[e] = best;
  }
  __syncthreads();
  for (int e = tid; e < 2048; e += 256){
    int nl = e >> 7, o = e & 127;
    const float* w = Wp + o*128;
    const float* fp = fpre + nl*128;
    float acc = bp[o];
    for (int c2 = 0; c2 < 128; ++c2) acc += fp[c2]*w[c2];
    f[((b*NPTS + n0 + nl) << 7) + o] = acc;
  }
}

// ---------------- per-batch grid bounds (fp64 deciders) ----------------
__device__ __forceinline__ float blk_red(float val, float* red, int tid, bool ismin){
  for (int s = 32; s; s >>= 1){
    float o = __shfl_xor(val, s);
    val = ismin ? fminf(val, o) : fmaxf(val, o);
  }
  if ((tid & 63) == 0) red[tid >> 6] = val;
  __syncthreads();
  float r = ismin ? fminf(fminf(red[0],red[1]), fminf(red[2],red[3]))
                  : fmaxf(fmaxf(red[0],red[1]), fmaxf(red[2],red[3]));
  __syncthreads();
  return r;
}

__global__ __launch_bounds__(256) void bounds_k(const float* __restrict__ pc, double* __restrict__ bnd){
  __shared__ float red[4];
  int b = blockIdx.x;
  int tid = threadIdx.x;
  const float* p = pc + (size_t)b*NPTS*3;
  float mn0 = 3.0e38f, mn1 = 3.0e38f, mx0 = -3.0e38f, mx1 = -3.0e38f;
  for (int n = tid; n < NPTS; n += 256){
    float a = p[n*3], c = p[n*3+1];
    mn0 = fminf(mn0, a); mx0 = fmaxf(mx0, a);
    mn1 = fminf(mn1, c); mx1 = fmaxf(mx1, c);
  }
  mn0 = blk_red(mn0, red, tid, true);
  mx0 = blk_red(mx0, red, tid, false);
  mn1 = blk_red(mn1, red, tid, true);
  mx1 = blk_red(mx1, red, tid, false);
  double e0 = (double)mx0 - (double)mn0;
  double e1 = (double)mx1 - (double)mn1;
  double gs = (e0 > e1 ? e0 : e1) / 197.0;
  float imn0 = 3.0e38f, imx0 = -3.0e38f, imn1 = 3.0e38f, imx1 = -3.0e38f;
  for (int n = tid; n < NPTS; n += 256){
    float i0 = (float)floor(((double)p[n*3]   - (double)mn0) / gs);
    float i1 = (float)floor(((double)p[n*3+1] - (double)mn1) / gs);
    imn0 = fminf(imn0, i0); imx0 = fmaxf(imx0, i0);
    imn1 = fminf(imn1, i1); imx1 = fmaxf(imx1, i1);
  }
  imn0 = blk_red(imn0, red, tid, true);
  imx0 = blk_red(imx0, red, tid, false);
  imn1 = blk_red(imn1, red, tid, true);
  imx1 = blk_red(imx1, red, tid, false);
  if (tid == 0){
    float c0 = floorf((imx0 + 2.0f + imn0) / 2.0f);
    float c1 = floorf((imx1 + 2.0f + imn1) / 2.0f);
    bnd[b*8+0] = (double)mn0;
    bnd[b*8+1] = (double)mn1;
    bnd[b*8+2] = gs;
    bnd[b*8+3] = (double)(100.0f - c0 - 1.0f);
    bnd[b*8+4] = (double)(100.0f - c1 - 1.0f);
  }
}

// ---------------- scatter into fp32 halo buffer (B,226,226,128) ----------------
__global__ __launch_bounds__(256) void scatter_k(const float* __restrict__ pc, const double* __restrict__ bnd,
    const float* __restrict__ f, float* __restrict__ resf){
  int wave = threadIdx.x >> 6, lane = threadIdx.x & 63;
  int q = blockIdx.x*4 + wave;
  int b = q >> 11;
  const double* bd = bnd + b*8;
  double gs = bd[2];
  double px = pc[(size_t)q*3], py = pc[(size_t)q*3+1];
  int ix0 = (int)floor((px - bd[0]) / gs);
  int iy0 = (int)floor((py - bd[1]) / gs);
  int cx = ix0 + 1 + (int)bd[3];
  int cy = iy0 + 1 + (int)bd[4];
  float f0 = f[(size_t)q*128 + lane];
  float f1 = f[(size_t)q*128 + 64 + lane];
  for (int t = 0; t < 9; ++t){
    int gx = cx + t/3 - 1;
    int gy = cy + t%3 - 1;
    if ((unsigned)gx < 200u && (unsigned)gy < 200u){
      float* cell = resf + (((size_t)b*226 + (gx+13))*226 + (gy+13))*128;
      atomicAdd(cell + lane, f0);
      atomicAdd(cell + 64 + lane, f1);
    }
  }
}

// ---------------- zero the fp32 border ring of the h1f halo buffer ----------------
__global__ __launch_bounds__(256) void zbordf_k(float* __restrict__ h1f){
  int i = blockIdx.x*256 + threadIdx.x;   // 4*900 border pixels * 32 float4 chunks
  if (i >= BATCH*900*32) return;
  int chunk = i & 31;
  int pix = i >> 5;
  int b = pix / 900;
  int p = pix - b*900;
  int y, x;
  if (p < 226){ y = 0; x = p; }
  else if (p < 452){ y = 225; x = p - 226; }
  else if (p < 676){ x = 0; y = 1 + (p - 452); }
  else { x = 225; y = 1 + (p - 676); }
  float4 z = {0.f, 0.f, 0.f, 0.f};
  *(float4*)(h1f + (((size_t)b*226 + y)*226 + x)*128 + chunk*4) = z;
}

// ---------------- 3x3 conv, PURE bf16 MFMA implicit GEMM ----------------
// P8J2, fp32 halo in/out, weights from L2, fp32 epilogue, rolled tap loop,
// 64-channel two-half staging (inb 23 KB). Round-18 change: explicit depth-1
// B-fragment software pipeline — pb0/pb1 hold step s+1's weights while step s
// computes, hiding the ~200cyc L2 latency under 16 MFMAs + ds_reads. The
// weight buffers are padded by one tap so the final prefetch is in-bounds.
// in: fp32 halo (B,226,226,128). w: [10(t padded)][oc(128)][ic(128)] bf16.
// FUSE_FINAL=0: out fp32 halo (write interior), relu.
// FUSE_FINAL=1: += res (fp32 halo), relu, folded 1x1 + sigmoid + normalize -> d_out.
template<int FUSE_FINAL>
__global__ __launch_bounds__(256) void conv3_k(
    const float* __restrict__ in, const unsigned short* __restrict__ w,
    const float* __restrict__ bias, const float* __restrict__ res,
    float* __restrict__ out, const float* __restrict__ Wf, const float* __restrict__ bff){
  __shared__ __align__(16) char inb[23040];   // 10*18 pix * 64ch bf16 (128B/pix), x-swizzled
  __shared__ float facc[8][16][3];            // fused-final pixel accumulators
  int tx = blockIdx.x, ty = blockIdx.y, b = blockIdx.z;
  int tid = threadIdx.x;
  int lane = tid & 63, wave = tid >> 6;
  int lo = lane & 15, hi = lane >> 4;
  const int y0 = ty*8, x0 = tx*16;
  const float* ibase = in + (size_t)b*226*226*128;
  if (FUSE_FINAL){
    for (int e = tid; e < 384; e += 256) ((float*)facc)[e] = 0.f;
  }
  f32x4 acc[8][2];
  f32x4 zero = {0.f, 0.f, 0.f, 0.f};
  #pragma unroll
  for (int i = 0; i < 8; ++i){ acc[i][0] = zero; acc[i][1] = zero; }
  int ocb = wave*32;
  int boff0 = (ocb + lo)*128 + hi*8;
  int boff1 = (ocb + 16 + lo)*128 + hi*8;
  for (int ih2 = 0; ih2 < 2; ++ih2){
    __syncthreads();   // previous half's readers done (also orders facc zeroing)
    for (int ch = tid; ch < 1440; ch += 256){
      int pix = ch >> 3, ci = ch & 7;
      int iy = pix/18, ix = pix - iy*18;
      const float* src = ibase + ((size_t)(y0+iy)*226 + (x0+ix))*128 + ih2*64 + ci*8;
      float4 v0 = *(const float4*)(src);
      float4 v1 = *(const float4*)(src + 4);
      unsigned short h8[8];
      h8[0]=f2bf(v0.x); h8[1]=f2bf(v0.y); h8[2]=f2bf(v0.z); h8[3]=f2bf(v0.w);
      h8[4]=f2bf(v1.x); h8[5]=f2bf(v1.y); h8[6]=f2bf(v1.z); h8[7]=f2bf(v1.w);
      *(bf16x8*)(inb + ((pix*128 + ci*16) ^ ((ix & 7) << 4))) = *(bf16x8*)h8;
    }
    __syncthreads();   // staged half visible
    const unsigned short* wb_ = w + ih2*64;
    bf16x8 pb0 = *(const bf16x8*)(wb_ + boff0);   // step 0 = (t=0,kc=0)
    bf16x8 pb1 = *(const bf16x8*)(wb_ + boff1);
    #pragma unroll 1
    for (int t = 0; t < 9; ++t){
      int dy = t/3, dx = t - 3*dy;
      int ix = lo + dx;
      int swz = (ix & 7) << 4;
      #pragma unroll
      for (int kc = 0; kc < 2; ++kc){
        bf16x8 b0 = pb0, b1 = pb1;
        // prefetch step t*2+kc+1 (tap 9 is padding — read, never used)
        int nstep = t*2 + kc + 1;
        size_t nb = (size_t)(nstep >> 1)*16384 + (nstep & 1)*32;
        pb0 = *(const bf16x8*)(wb_ + nb + boff0);
        pb1 = *(const bf16x8*)(wb_ + nb + boff1);
        #pragma unroll
        for (int py = 0; py < 8; ++py){
          bf16x8 a = *(const bf16x8*)(inb + ((((py+dy)*18 + ix)*128 + kc*64 + hi*16) ^ swz));
          acc[py][0] = __builtin_amdgcn_mfma_f32_16x16x32_bf16(a, b0, acc[py][0], 0, 0, 0);
          acc[py][1] = __builtin_amdgcn_mfma_f32_16x16x32_bf16(a, b1, acc[py][1], 0, 0, 0);
        }
      }
    }
  }
  if (FUSE_FINAL){
    __syncthreads();
    float wf0[2], wf1[2], wf2[2];
    #pragma unroll
    for (int j = 0; j < 2; ++j){
      int oc = ocb + j*16 + lo;
      wf0[j] = Wf[oc]; wf1[j] = Wf[128+oc]; wf2[j] = Wf[256+oc];
    }
    #pragma unroll
    for (int py = 0; py < 8; ++py){
      int gy = ty*8 + py;
      #pragma unroll
      for (int r = 0; r < 4; ++r){
        int px = hi*4 + r;
        int gx = tx*16 + px;
        float p0 = 0.f, p1 = 0.f, p2 = 0.f;
        #pragma unroll
        for (int j = 0; j < 2; ++j){
          int oc = ocb + j*16 + lo;
          float val = acc[py][j][r] + bias[oc]
                    + res[(((size_t)b*226 + gy+1)*226 + (gx+1))*128 + oc];
          val = fmaxf(val, 0.f);
          p0 += val*wf0[j]; p1 += val*wf1[j]; p2 += val*wf2[j];
        }
        #pragma unroll
        for (int s = 1; s < 16; s <<= 1){
          p0 += __shfl_xor(p0, s);
          p1 += __shfl_xor(p1, s);
          p2 += __shfl_xor(p2, s);
        }
        if (lo == 0){
          atomicAdd(&facc[py][px][0], p0);
          atomicAdd(&facc[py][px][1], p1);
          atomicAdd(&facc[py][px][2], p2);
        }
      }
    }
    __syncthreads();
    const float mean3[3] = {0.485f, 0.456f, 0.406f};
    const float istd3[3] = {1.0f/0.229f, 1.0f/0.224f, 1.0f/0.225f};
    for (int e = tid; e < 384; e += 256){
      int py = e / 48;
      int rem = e - py*48;
      int px = rem / 3;
      int ch = rem - px*3;
      float a = facc[py][px][ch] + bff[ch];
      float s = 1.0f/(1.0f + expf(-a));
      out[(((size_t)(b*3 + ch))*224 + (ty*8+py))*224 + (tx*16+px)] = (s - mean3[ch])*istd3[ch];
    }
  } else {
    #pragma unroll
    for (int py = 0; py < 8; ++py){
      int gy = ty*8 + py;
      #pragma unroll
      for (int j = 0; j < 2; ++j){
        int oc = ocb + j*16 + lo;
        float bs = bias[oc];
        #pragma unroll
        for (int r = 0; r < 4; ++r){
          int px = hi*4 + r;
          int gx = tx*16 + px;
          float val = fmaxf(acc[py][j][r] + bs, 0.f);
          out[(((size_t)b*226 + gy+1)*226 + (gx+1))*128 + oc] = val;
        }
      }
    }
  }
}

extern "C" void kernel_launch(void* const* d_in, const int* in_sizes, int n_in,
                              void* d_out, int out_size, void* d_ws, size_t ws_size,
                              hipStream_t stream){
  const float* opc   = (const float*)d_in[0];
  const float* pc    = (const float*)d_in[1];
  const float* Win   = (const float*)d_in[2];
  const float* bin   = (const float*)d_in[3];
  const float* Wg    = (const float*)d_in[4];
  const float* gng   = (const float*)d_in[5];
  const float* gnb   = (const float*)d_in[6];
  const float* Wp    = (const float*)d_in[7];
  const float* bp    = (const float*)d_in[8];
  const float* W1    = (const float*)d_in[9];
  const float* g1    = (const float*)d_in[10];
  const float* b1    = (const float*)d_in[11];
  const float* m1    = (const float*)d_in[12];
  const float* v1    = (const float*)d_in[13];
  const float* W2    = (const float*)d_in[14];
  const float* g2    = (const float*)d_in[15];
  const float* b2    = (const float*)d_in[16];
  const float* m2    = (const float*)d_in[17];
  const float* v2    = (const float*)d_in[18];
  const float* Wimgc = (const float*)d_in[19];
  const float* bimgc = (const float*)d_in[20];
  const float* Wimg  = (const float*)d_in[21];
  const float* bimg  = (const float*)d_in[22];

  char* ws = (char*)d_ws;
  size_t off = 0;
  auto alloc = [&](size_t bytes)->char*{
    char* p = ws + off;
    off += (bytes + 255) & ~(size_t)255;
    return p;
  };
  // total ws usage ~224 MB (round-4/6 footprint ran OK)
  float* x      = (float*)alloc((size_t)BATCH*NPTS*64*4);
  double* sq    = (double*)alloc((size_t)BATCH*NPTS*8);
  int*   idx    = (int*)  alloc((size_t)BATCH*NPTS*KNN*4);
  float* u      = (float*)alloc((size_t)BATCH*NPTS*128*4);
  float* v      = (float*)alloc((size_t)BATCH*NPTS*128*4);
  float* f      = (float*)alloc((size_t)BATCH*NPTS*128*4);
  float* sums   = (float*)alloc(256);
  double* bnd   = (double*)alloc(256);
  float* bias1  = (float*)alloc(512);
  float* bias2  = (float*)alloc(512);
  float* Wf     = (float*)alloc(2048);
  float* bff    = (float*)alloc(256);
  unsigned short* w1f = (unsigned short*)alloc((size_t)10*16384*2);  // +1 padding tap
  unsigned short* w2f = (unsigned short*)alloc((size_t)10*16384*2);  // +1 padding tap
  float* resf = (float*)alloc((size_t)BATCH*226*226*128*4);
  float* h1f  = (float*)alloc((size_t)BATCH*226*226*128*4);
  float* out = (float*)d_out;

  hipMemsetAsync(sums, 0, 256, stream);
  hipMemsetAsync(resf, 0, (size_t)BATCH*226*226*128*4, stream);

  fold_wpk<<<576, 256, 0, stream>>>(W1, g1, b1, m1, v1, w1f, bias1);
  fold_wpk<<<576, 256, 0, stream>>>(W2, g2, b2, m2, v2, w2f, bias2);
  fold_img<<<2, 256, 0, stream>>>(Wimgc, bimgc, Wimg, bimg, Wf, bff);
  zbordf_k<<<450, 256, 0, stream>>>(h1f);
  prep_x<<<32, 256, 0, stream>>>(opc, Win, bin, x, sq);
  prep_uv<<<4096, 256, 0, stream>>>(x, Wg, u, v);
  knn_k<<<4096, 128, 0, stream>>>(opc, sq, idx);
  stats_k<<<512, 256, 0, stream>>>(u, v, idx, sums);
  fcomp_k<<<512, 256, 0, stream>>>(u, v, idx, sums, gng, gnb, Wp, bp, f);
  bounds_k<<<4, 256, 0, stream>>>(pc, bnd);
  scatter_k<<<2048, 256, 0, stream>>>(pc, bnd, f, resf);
  conv3_k<0><<<dim3(14,28,4), 256, 0, stream>>>(resf, w1f, bias1, nullptr, h1f, nullptr, nullptr);
  conv3_k<1><<<dim3(14,28,4), 256, 0, stream>>>(h1f, w2f, bias2, resf, out, Wf, bff);
}

// Round 19
// 537.339 us; speedup vs baseline: 1.0792x; 1.0792x over previous
//
#include <hip/hip_runtime.h>
#include <stdint.h>

#define NPTS 2048
#define BATCH 4
#define KNN 20
#define EPSV 1e-5f

typedef short bf16x8 __attribute__((ext_vector_type(8)));
typedef unsigned short u16x8 __attribute__((ext_vector_type(8)));
typedef float f32x4 __attribute__((ext_vector_type(4)));

__device__ __forceinline__ unsigned short f2bf(float f){
  union { float f; uint32_t u; } x; x.f = f;
  uint32_t u = x.u;
  uint32_t r = (u + 0x7fffu + ((u >> 16) & 1u)) >> 16;
  return (unsigned short)r;
}
__device__ __forceinline__ float bf2f(unsigned short h){
  union { uint32_t u; float f; } x; x.u = ((uint32_t)h) << 16;
  return x.f;
}

// ---------------- weight folding: bn-fold -> bf16 [t][oc(128)][ic(128)] ----------------
__global__ __launch_bounds__(256) void fold_wpk(const float* __restrict__ W, const float* __restrict__ g,
    const float* __restrict__ bb, const float* __restrict__ m, const float* __restrict__ vv,
    unsigned short* __restrict__ w, float* __restrict__ bias){
  int e = blockIdx.x*256 + threadIdx.x;
  if (e < 128){
    float s = g[e] / sqrtf(vv[e] + EPSV);
    bias[e] = bb[e] - m[e]*s;
  }
  if (e < 9*128*128){
    int t = e >> 14;
    int o = (e >> 7) & 127;
    int i = e & 127;
    int kh = t/3, kw = t - 3*kh;
    float s = g[o] / sqrtf(vv[o] + EPSV);
    float wv = W[((o*128 + i)*3 + kh)*3 + kw] * s;
    w[(t*128 + o)*128 + i] = f2bf(wv);
  }
}

__global__ __launch_bounds__(256) void fold_img(const float* __restrict__ Wimgc, const float* __restrict__ bimgc,
    const float* __restrict__ Wimg, const float* __restrict__ bimg,
    float* __restrict__ Wf, float* __restrict__ bf){
  int e = blockIdx.x*256 + threadIdx.x;
  if (e < 384){
    int j = e >> 7, c = e & 127;
    float s = 0.f;
    for (int o = 0; o < 128; ++o) s += Wimg[j*128+o] * Wimgc[o*128+c];
    Wf[e] = s;
  }
  if (e < 3){
    float s = bimg[e];
    for (int o = 0; o < 128; ++o) s += Wimg[e*128+o] * bimgc[o];
    bf[e] = s;
  }
}

// ---------------- point features (sq in fp64 to match numpy ref) ----------------
__global__ __launch_bounds__(256) void prep_x(const float* __restrict__ opc, const float* __restrict__ Win,
    const float* __restrict__ bin, float* __restrict__ x, double* __restrict__ sq){
  int p = blockIdx.x*256 + threadIdx.x;
  if (p >= BATCH*NPTS) return;
  float a = opc[p*3], b = opc[p*3+1], c = opc[p*3+2];
  double ad = a, bd = b, cd = c;
  sq[p] = (ad*ad + bd*bd) + cd*cd;
  for (int o = 0; o < 64; ++o)
    x[p*64+o] = a*Win[o*3] + b*Win[o*3+1] + c*Win[o*3+2] + bin[o];
}

__global__ __launch_bounds__(256) void prep_uv(const float* __restrict__ x, const float* __restrict__ Wg,
    float* __restrict__ u, float* __restrict__ v){
  int e = blockIdx.x*256 + threadIdx.x;
  if (e >= BATCH*NPTS*128) return;
  int p = e >> 7, o = e & 127;
  const float* xr = x + p*64;
  const float* w = Wg + o*128;
  float su = 0.f, sv = 0.f;
  for (int c = 0; c < 64; ++c){
    float xv = xr[c];
    sv += w[c]*xv;
    su += (w[64+c] - w[c])*xv;
  }
  u[e] = su; v[e] = sv;
}

// ---------------- exact top-K (smallest d2), fp64, quarter-cached minima ----------------
__device__ __forceinline__ void knn_merge(double va, int ia, double vb, int ib,
                                          double& vo, int& io){
  if (vb < va || (vb == va && ib < ia)){ vo = vb; io = ib; }
  else { vo = va; io = ia; }
}

__device__ __forceinline__ void knn_scan_q(const double* __restrict__ d, int lane, int qt,
                                           double& vq, int& iq){
  double v0 = 1.0e300, v1 = 1.0e300;
  int i0 = -1, i1 = -1;
  int kb = qt*8;
  #pragma unroll
  for (int k2 = 0; k2 < 8; k2 += 2){
    int m0 = lane + (kb + k2)*64;
    int m1 = lane + (kb + k2 + 1)*64;
    double a0 = d[m0];
    double a1 = d[m1];
    if (a0 < v0){ v0 = a0; i0 = m0; }
    if (a1 < v1){ v1 = a1; i1 = m1; }
  }
  knn_merge(v0, i0, v1, i1, vq, iq);
}

__global__ __launch_bounds__(128) void knn_k(const float* __restrict__ pc, const double* __restrict__ sq,
    int* __restrict__ idx){
  __shared__ double dd[2][NPTS];
  int wave = threadIdx.x >> 6, lane = threadIdx.x & 63;
  int q = blockIdx.x*2 + wave;
  int b = q >> 11, n = q & 2047;
  const float* pb = pc + (size_t)b*NPTS*3;
  const double* sqb = sq + b*NPTS;
  double qx = pb[n*3], qy = pb[n*3+1], qz = pb[n*3+2];
  double sn = sqb[n];
  double* d = dd[wave];
  double vq[4]; int iq[4];
  #pragma unroll
  for (int t = 0; t < 4; ++t){ vq[t] = 1.0e300; iq[t] = -1; }
  #pragma unroll
  for (int k = 0; k < 32; ++k){
    int m = lane + k*64;
    double px = pb[m*3], py = pb[m*3+1], pz = pb[m*3+2];
    double dot = (qx*px + qy*py) + qz*pz;
    double val = (sn + sqb[m]) - 2.0*dot;
    d[m] = val;
    const int qt = k >> 3;
    if (val < vq[qt]){ vq[qt] = val; iq[qt] = m; }
  }
  double bv; int bi;
  {
    double m0, m1; int j0, j1;
    knn_merge(vq[0], iq[0], vq[1], iq[1], m0, j0);
    knn_merge(vq[2], iq[2], vq[3], iq[3], m1, j1);
    knn_merge(m0, j0, m1, j1, bv, bi);
  }
  for (int it = 0; it < KNN; ++it){
    double v = bv; int i = bi;
    #pragma unroll
    for (int s = 32; s; s >>= 1){
      double ov = __shfl_xor(v, s);
      int oi = __shfl_xor(i, s);
      if (ov < v || (ov == v && oi < i)){ v = ov; i = oi; }
    }
    if (lane == 0) idx[q*KNN + it] = i;
    if ((i & 63) == lane){
      d[i] = 1.0e300;
      int qt = i >> 9;
      knn_scan_q(d, lane, qt, vq[qt], iq[qt]);
      double m0, m1; int j0, j1;
      knn_merge(vq[0], iq[0], vq[1], iq[1], m0, j0);
      knn_merge(vq[2], iq[2], vq[3], iq[3], m1, j1);
      knn_merge(m0, j0, m1, j1, bv, bi);
    }
  }
}

// ---------------- groupnorm statistics + monotone max-commute pooling ----------------
// z = lrelu((y-mu)*inv*gg + gb) is monotone in y for gg>=0 (anti for gg<0),
// so max_k z = z(max_k y) (resp. min). Record ysel = (gg>=0 ? max_k y : min_k y)
// here, where the gather already happens; fcomp then needs no gather at all.
__global__ __launch_bounds__(256) void stats_k(const float* __restrict__ u, const float* __restrict__ v,
    const int* __restrict__ idx, const float* __restrict__ gng,
    float* __restrict__ sums, float* __restrict__ ysel){
  int blk = blockIdx.x;
  int b = blk >> 7;
  int n0 = (blk & 127) * 16;
  int tid = threadIdx.x;
  __shared__ int sidx[16*KNN];
  for (int i = tid; i < 16*KNN; i += 256)
    sidx[i] = idx[(b*NPTS + n0 + i/KNN)*KNN + (i % KNN)];
  __syncthreads();
  int c = tid & 127;
  int nh = tid >> 7;                 // nl half: [nh*8, nh*8+8)
  float gg = gng[c];
  float s = 0.f, ss = 0.f;
  for (int nl = nh*8; nl < nh*8 + 8; ++nl){
    float uv = u[((b*NPTS + n0 + nl) << 7) + c];
    float best = -3.0e38f, worst = 3.0e38f;
    for (int k = 0; k < KNN; ++k){
      int m = sidx[nl*KNN + k];
      float y = v[((b*NPTS + m) << 7) + c] + uv;
      s += y; ss += y*y;
      best = fmaxf(best, y);
      worst = fminf(worst, y);
    }
    ysel[((b*NPTS + n0 + nl) << 7) + c] = (gg >= 0.f) ? best : worst;
  }
  for (int msk = 1; msk < 32; msk <<= 1){
    s += __shfl_xor(s, msk);
    ss += __shfl_xor(ss, msk);
  }
  if ((tid & 31) == 0){
    int g = c >> 5;
    atomicAdd(&sums[(b*4 + g)*2 + 0], s);
    atomicAdd(&sums[(b*4 + g)*2 + 1], ss);
  }
}

// ---------------- normalize + lrelu (on pre-pooled ysel) + proj ----------------
__global__ __launch_bounds__(256) void fcomp_k(const float* __restrict__ ysel,
    const float* __restrict__ sums,
    const float* __restrict__ gng, const float* __restrict__ gnb,
    const float* __restrict__ Wp, const float* __restrict__ bp, float* __restrict__ f){
  int blk = blockIdx.x;
  int b = blk >> 7;
  int n0 = (blk & 127) * 16;
  int tid = threadIdx.x;
  __shared__ float fpre[16*128];
  __shared__ float smu[4], sinv[4];
  if (tid < 4){
    const float cnt = 2048.0f*20.0f*32.0f;
    float sm = sums[(b*4 + tid)*2 + 0];
    float s2 = sums[(b*4 + tid)*2 + 1];
    float mu = sm/cnt;
    float var = s2/cnt - mu*mu;
    smu[tid] = mu;
    sinv[tid] = 1.0f / sqrtf(var + EPSV);
  }
  __syncthreads();
  for (int e = tid; e < 2048; e += 256){
    int nl = e >> 7, c = e & 127;
    int g = c >> 5;
    float y = ysel[((b*NPTS + n0 + nl) << 7) + c];
    float z = (y - smu[g])*sinv[g]*gng[c] + gnb[c];
    z = z >= 0.f ? z : 0.2f*z;
    fpre[e] = z;
  }
  __syncthreads();
  for (int e = tid; e < 2048; e += 256){
    int nl = e >> 7, o = e & 127;
    const float* w = Wp + o*128;
    const float* fp = fpre + nl*128;
    float acc = bp[o];
    for (int c2 = 0; c2 < 128; ++c2) acc += fp[c2]*w[c2];
    f[((b*NPTS + n0 + nl) << 7) + o] = acc;
  }
}

// ---------------- per-batch grid bounds (fp64 deciders) ----------------
__device__ __forceinline__ float blk_red(float val, float* red, int tid, bool ismin){
  for (int s = 32; s; s >>= 1){
    float o = __shfl_xor(val, s);
    val = ismin ? fminf(val, o) : fmaxf(val, o);
  }
  if ((tid & 63) == 0) red[tid >> 6] = val;
  __syncthreads();
  float r = ismin ? fminf(fminf(red[0],red[1]), fminf(red[2],red[3]))
                  : fmaxf(fmaxf(red[0],red[1]), fmaxf(red[2],red[3]));
  __syncthreads();
  return r;
}

__global__ __launch_bounds__(256) void bounds_k(const float* __restrict__ pc, double* __restrict__ bnd){
  __shared__ float red[4];
  int b = blockIdx.x;
  int tid = threadIdx.x;
  const float* p = pc + (size_t)b*NPTS*3;
  float mn0 = 3.0e38f, mn1 = 3.0e38f, mx0 = -3.0e38f, mx1 = -3.0e38f;
  for (int n = tid; n < NPTS; n += 256){
    float a = p[n*3], c = p[n*3+1];
    mn0 = fminf(mn0, a); mx0 = fmaxf(mx0, a);
    mn1 = fminf(mn1, c); mx1 = fmaxf(mx1, c);
  }
  mn0 = blk_red(mn0, red, tid, true);
  mx0 = blk_red(mx0, red, tid, false);
  mn1 = blk_red(mn1, red, tid, true);
  mx1 = blk_red(mx1, red, tid, false);
  double e0 = (double)mx0 - (double)mn0;
  double e1 = (double)mx1 - (double)mn1;
  double gs = (e0 > e1 ? e0 : e1) / 197.0;
  float imn0 = 3.0e38f, imx0 = -3.0e38f, imn1 = 3.0e38f, imx1 = -3.0e38f;
  for (int n = tid; n < NPTS; n += 256){
    float i0 = (float)floor(((double)p[n*3]   - (double)mn0) / gs);
    float i1 = (float)floor(((double)p[n*3+1] - (double)mn1) / gs);
    imn0 = fminf(imn0, i0); imx0 = fmaxf(imx0, i0);
    imn1 = fminf(imn1, i1); imx1 = fmaxf(imx1, i1);
  }
  imn0 = blk_red(imn0, red, tid, true);
  imx0 = blk_red(imx0, red, tid, false);
  imn1 = blk_red(imn1, red, tid, true);
  imx1 = blk_red(imx1, red, tid, false);
  if (tid == 0){
    float c0 = floorf((imx0 + 2.0f + imn0) / 2.0f);
    float c1 = floorf((imx1 + 2.0f + imn1) / 2.0f);
    bnd[b*8+0] = (double)mn0;
    bnd[b*8+1] = (double)mn1;
    bnd[b*8+2] = gs;
    bnd[b*8+3] = (double)(100.0f - c0 - 1.0f);
    bnd[b*8+4] = (double)(100.0f - c1 - 1.0f);
  }
}

// ---------------- scatter into fp32 halo buffer (B,226,226,128) ----------------
__global__ __launch_bounds__(256) void scatter_k(const float* __restrict__ pc, const double* __restrict__ bnd,
    const float* __restrict__ f, float* __restrict__ resf){
  int wave = threadIdx.x >> 6, lane = threadIdx.x & 63;
  int q = blockIdx.x*4 + wave;
  int b = q >> 11;
  const double* bd = bnd + b*8;
  double gs = bd[2];
  double px = pc[(size_t)q*3], py = pc[(size_t)q*3+1];
  int ix0 = (int)floor((px - bd[0]) / gs);
  int iy0 = (int)floor((py - bd[1]) / gs);
  int cx = ix0 + 1 + (int)bd[3];
  int cy = iy0 + 1 + (int)bd[4];
  float f0 = f[(size_t)q*128 + lane];
  float f1 = f[(size_t)q*128 + 64 + lane];
  for (int t = 0; t < 9; ++t){
    int gx = cx + t/3 - 1;
    int gy = cy + t%3 - 1;
    if ((unsigned)gx < 200u && (unsigned)gy < 200u){
      float* cell = resf + (((size_t)b*226 + (gx+13))*226 + (gy+13))*128;
      atomicAdd(cell + lane, f0);
      atomicAdd(cell + 64 + lane, f1);
    }
  }
}

// ---------------- zero the bf16 border ring of the h1b halo buffer ----------------
__global__ __launch_bounds__(256) void zbordb_k(unsigned short* __restrict__ h1b){
  int i = blockIdx.x*256 + threadIdx.x;   // 4*900 border pixels * 16 chunks of 16B
  if (i >= BATCH*900*16) return;
  int chunk = i & 15;
  int pix = i >> 4;
  int b = pix / 900;
  int p = pix - b*900;
  int y, x;
  if (p < 226){ y = 0; x = p; }
  else if (p < 452){ y = 225; x = p - 226; }
  else if (p < 676){ x = 0; y = 1 + (p - 452); }
  else { x = 225; y = 1 + (p - 676); }
  u16x8 z = {0,0,0,0,0,0,0,0};
  *(u16x8*)(h1b + (((size_t)b*226 + y)*226 + x)*128 + chunk*8) = z;
}

// ---------------- 3x3 conv, PURE bf16 MFMA implicit GEMM ----------------
// P8J2, weights from L2 (depth-1 B prefetch), rolled tap loop, 64-ch two-half
// staging. Round-19: bf16 h1 handoff (bit-identical — conv2 staged f2bf anyway):
// IN_BF16=0 input fp32 halo (convert during staging); =1 input bf16 halo (pure copy).
// FUSE_FINAL=0: relu -> bf16 halo out via coalesced LDS bounce.
// FUSE_FINAL=1: += res (fp32 halo), relu, folded 1x1 + sigmoid + normalize -> d_out.
template<int IN_BF16, int FUSE_FINAL>
__global__ __launch_bounds__(256) void conv3_k(
    const float* __restrict__ inf, const unsigned short* __restrict__ inh,
    const unsigned short* __restrict__ w, const float* __restrict__ bias,
    const float* __restrict__ res, float* __restrict__ out, unsigned short* __restrict__ outh,
    const float* __restrict__ Wf, const float* __restrict__ bff){
  __shared__ __align__(16) char inb[32768];   // staging (23 KB used) / output bounce (32 KB)
  __shared__ float facc[8][16][3];
  int tx = blockIdx.x, ty = blockIdx.y, b = blockIdx.z;
  int tid = threadIdx.x;
  int lane = tid & 63, wave = tid >> 6;
  int lo = lane & 15, hi = lane >> 4;
  const int y0 = ty*8, x0 = tx*16;
  const float* ibase = IN_BF16 ? nullptr : (inf + (size_t)b*226*226*128);
  const unsigned short* ihb = IN_BF16 ? (inh + (size_t)b*226*226*128) : nullptr;
  if (FUSE_FINAL){
    for (int e = tid; e < 384; e += 256) ((float*)facc)[e] = 0.f;
  }
  f32x4 acc[8][2];
  f32x4 zero = {0.f, 0.f, 0.f, 0.f};
  #pragma unroll
  for (int i = 0; i < 8; ++i){ acc[i][0] = zero; acc[i][1] = zero; }
  int ocb = wave*32;
  int boff0 = (ocb + lo)*128 + hi*8;
  int boff1 = (ocb + 16 + lo)*128 + hi*8;
  for (int ih2 = 0; ih2 < 2; ++ih2){
    __syncthreads();   // previous half's readers done (also orders facc zeroing)
    for (int ch = tid; ch < 1440; ch += 256){
      int pix = ch >> 3, ci = ch & 7;
      int iy = pix/18, ix = pix - iy*18;
      size_t poff = (size_t)(y0+iy)*226 + (x0+ix);
      int dst = (pix*128 + ci*16) ^ ((ix & 7) << 4);
      if (IN_BF16){
        *(u16x8*)(inb + dst) = *(const u16x8*)(ihb + poff*128 + ih2*64 + ci*8);
      } else {
        const float* src = ibase + poff*128 + ih2*64 + ci*8;
        float4 v0 = *(const float4*)(src);
        float4 v1 = *(const float4*)(src + 4);
        unsigned short h8[8];
        h8[0]=f2bf(v0.x); h8[1]=f2bf(v0.y); h8[2]=f2bf(v0.z); h8[3]=f2bf(v0.w);
        h8[4]=f2bf(v1.x); h8[5]=f2bf(v1.y); h8[6]=f2bf(v1.z); h8[7]=f2bf(v1.w);
        *(bf16x8*)(inb + dst) = *(bf16x8*)h8;
      }
    }
    __syncthreads();   // staged half visible
    const unsigned short* wb_ = w + ih2*64;
    bf16x8 pb0 = *(const bf16x8*)(wb_ + boff0);
    bf16x8 pb1 = *(const bf16x8*)(wb_ + boff1);
    #pragma unroll 1
    for (int t = 0; t < 9; ++t){
      int dy = t/3, dx = t - 3*dy;
      int ix = lo + dx;
      int swz = (ix & 7) << 4;
      #pragma unroll
      for (int kc = 0; kc < 2; ++kc){
        bf16x8 b0 = pb0, b1 = pb1;
        int nstep = t*2 + kc + 1;
        size_t nb = (size_t)(nstep >> 1)*16384 + (nstep & 1)*32;
        pb0 = *(const bf16x8*)(wb_ + nb + boff0);
        pb1 = *(const bf16x8*)(wb_ + nb + boff1);
        #pragma unroll
        for (int py = 0; py < 8; ++py){
          bf16x8 a = *(const bf16x8*)(inb + ((((py+dy)*18 + ix)*128 + kc*64 + hi*16) ^ swz));
          acc[py][0] = __builtin_amdgcn_mfma_f32_16x16x32_bf16(a, b0, acc[py][0], 0, 0, 0);
          acc[py][1] = __builtin_amdgcn_mfma_f32_16x16x32_bf16(a, b1, acc[py][1], 0, 0, 0);
        }
      }
    }
  }
  if (FUSE_FINAL){
    __syncthreads();
    float wf0[2], wf1[2], wf2[2];
    #pragma unroll
    for (int j = 0; j < 2; ++j){
      int oc = ocb + j*16 + lo;
      wf0[j] = Wf[oc]; wf1[j] = Wf[128+oc]; wf2[j] = Wf[256+oc];
    }
    #pragma unroll
    for (int py = 0; py < 8; ++py){
      int gy = ty*8 + py;
      #pragma unroll
      for (int r = 0; r < 4; ++r){
        int px = hi*4 + r;
        int gx = tx*16 + px;
        float p0 = 0.f, p1 = 0.f, p2 = 0.f;
        #pragma unroll
        for (int j = 0; j < 2; ++j){
          int oc = ocb + j*16 + lo;
          float val = acc[py][j][r] + bias[oc]
                    + res[(((size_t)b*226 + gy+1)*226 + (gx+1))*128 + oc];
          val = fmaxf(val, 0.f);
          p0 += val*wf0[j]; p1 += val*wf1[j]; p2 += val*wf2[j];
        }
        #pragma unroll
        for (int s = 1; s < 16; s <<= 1){
          p0 += __shfl_xor(p0, s);
          p1 += __shfl_xor(p1, s);
          p2 += __shfl_xor(p2, s);
        }
        if (lo == 0){
          atomicAdd(&facc[py][px][0], p0);
          atomicAdd(&facc[py][px][1], p1);
          atomicAdd(&facc[py][px][2], p2);
        }
      }
    }
    __syncthreads();
    const float mean3[3] = {0.485f, 0.456f, 0.406f};
    const float istd3[3] = {1.0f/0.229f, 1.0f/0.224f, 1.0f/0.225f};
    for (int e = tid; e < 384; e += 256){
      int py = e / 48;
      int rem = e - py*48;
      int px = rem / 3;
      int ch = rem - px*3;
      float a = facc[py][px][ch] + bff[ch];
      float s = 1.0f/(1.0f + expf(-a));
      out[(((size_t)(b*3 + ch))*224 + (ty*8+py))*224 + (tx*16+px)] = (s - mean3[ch])*istd3[ch];
    }
  } else {
    // bounce: acc -> LDS [128 pix][128 ch] bf16 (32 KB), then coalesced 16B stores
    __syncthreads();   // all inb reads done
    #pragma unroll
    for (int py = 0; py < 8; ++py){
      #pragma unroll
      for (int j = 0; j < 2; ++j){
        int oc = ocb + j*16 + lo;
        float bs = bias[oc];
        #pragma unroll
        for (int r = 0; r < 4; ++r){
          int pix = py*16 + hi*4 + r;
          float val = fmaxf(acc[py][j][r] + bs, 0.f);
          *(unsigned short*)(inb + pix*256 + oc*2) = f2bf(val);
        }
      }
    }
    __syncthreads();
    unsigned short* ob = outh + (size_t)b*226*226*128;
    for (int e = tid; e < 2048; e += 256){
      int pix = e >> 4, cg = e & 15;
      int py = pix >> 4, px = pix & 15;
      u16x8 val = *(u16x8*)(inb + pix*256 + cg*16);
      *(u16x8*)(ob + (((size_t)(y0+py+1))*226 + (x0+px+1))*128 + cg*8) = val;
    }
  }
}

extern "C" void kernel_launch(void* const* d_in, const int* in_sizes, int n_in,
                              void* d_out, int out_size, void* d_ws, size_t ws_size,
                              hipStream_t stream){
  const float* opc   = (const float*)d_in[0];
  const float* pc    = (const float*)d_in[1];
  const float* Win   = (const float*)d_in[2];
  const float* bin   = (const float*)d_in[3];
  const float* Wg    = (const float*)d_in[4];
  const float* gng   = (const float*)d_in[5];
  const float* gnb   = (const float*)d_in[6];
  const float* Wp    = (const float*)d_in[7];
  const float* bp    = (const float*)d_in[8];
  const float* W1    = (const float*)d_in[9];
  const float* g1    = (const float*)d_in[10];
  const float* b1    = (const float*)d_in[11];
  const float* m1    = (const float*)d_in[12];
  const float* v1    = (const float*)d_in[13];
  const float* W2    = (const float*)d_in[14];
  const float* g2    = (const float*)d_in[15];
  const float* b2    = (const float*)d_in[16];
  const float* m2    = (const float*)d_in[17];
  const float* v2    = (const float*)d_in[18];
  const float* Wimgc = (const float*)d_in[19];
  const float* bimgc = (const float*)d_in[20];
  const float* Wimg  = (const float*)d_in[21];
  const float* bimg  = (const float*)d_in[22];

  char* ws = (char*)d_ws;
  size_t off = 0;
  auto alloc = [&](size_t bytes)->char*{
    char* p = ws + off;
    off += (bytes + 255) & ~(size_t)255;
    return p;
  };
  // ws total ~180 MB (well under the proven-OK 226 MB)
  float* x      = (float*)alloc((size_t)BATCH*NPTS*64*4);
  double* sq    = (double*)alloc((size_t)BATCH*NPTS*8);
  int*   idx    = (int*)  alloc((size_t)BATCH*NPTS*KNN*4);
  float* u      = (float*)alloc((size_t)BATCH*NPTS*128*4);
  float* v      = (float*)alloc((size_t)BATCH*NPTS*128*4);
  float* ysel   = (float*)alloc((size_t)BATCH*NPTS*128*4);
  float* f      = (float*)alloc((size_t)BATCH*NPTS*128*4);
  float* sums   = (float*)alloc(256);
  double* bnd   = (double*)alloc(256);
  float* bias1  = (float*)alloc(512);
  float* bias2  = (float*)alloc(512);
  float* Wf     = (float*)alloc(2048);
  float* bff    = (float*)alloc(256);
  unsigned short* w1f = (unsigned short*)alloc((size_t)10*16384*2);  // +1 padding tap
  unsigned short* w2f = (unsigned short*)alloc((size_t)10*16384*2);  // +1 padding tap
  float* resf         = (float*)alloc((size_t)BATCH*226*226*128*4);
  unsigned short* h1b = (unsigned short*)alloc((size_t)BATCH*226*226*128*2);
  float* out = (float*)d_out;

  hipMemsetAsync(sums, 0, 256, stream);
  hipMemsetAsync(resf, 0, (size_t)BATCH*226*226*128*4, stream);

  fold_wpk<<<576, 256, 0, stream>>>(W1, g1, b1, m1, v1, w1f, bias1);
  fold_wpk<<<576, 256, 0, stream>>>(W2, g2, b2, m2, v2, w2f, bias2);
  fold_img<<<2, 256, 0, stream>>>(Wimgc, bimgc, Wimg, bimg, Wf, bff);
  zbordb_k<<<225, 256, 0, stream>>>(h1b);
  prep_x<<<32, 256, 0, stream>>>(opc, Win, bin, x, sq);
  prep_uv<<<4096, 256, 0, stream>>>(x, Wg, u, v);
  knn_k<<<4096, 128, 0, stream>>>(opc, sq, idx);
  stats_k<<<512, 256, 0, stream>>>(u, v, idx, gng, sums, ysel);
  fcomp_k<<<512, 256, 0, stream>>>(ysel, sums, gng, gnb, Wp, bp, f);
  bounds_k<<<4, 256, 0, stream>>>(pc, bnd);
  scatter_k<<<2048, 256, 0, stream>>>(pc, bnd, f, resf);
  conv3_k<0,0><<<dim3(14,28,4), 256, 0, stream>>>(resf, nullptr, w1f, bias1, nullptr, nullptr, h1b, nullptr, nullptr);
  conv3_k<1,1><<<dim3(14,28,4), 256, 0, stream>>>(nullptr, h1b, w2f, bias2, resf, out, nullptr, Wf, bff);
}